// Round 4
// baseline (329.477 us; speedup 1.0000x reference)
//
#include <hip/hip_runtime.h>
#include <math.h>

// ---- problem constants ----
#define N_SAMP 441000
#define BATCH  16
#define N_OCT  55125           // octs (8-sample groups) per row
#define OPAD   55296           // padded octs: 216 chunks * 256
#define NMG    13824           // OPAD/4 macro-groups (4 octs each)
#define MGF    576             // floats per macro-group: 9 planes * 64 (16b*4slot)
#define MGB    2304            // bytes per macro-group
#define NWAVE  54              // 216 chunks / 4 per wave

#define A_AT  0.9977349953069123f
#define A_REL 0.9997732683378945f
#define OMA_AT  (1.0f - A_AT)
#define OMA_REL (1.0f - A_REL)

typedef float vf4 __attribute__((ext_vector_type(4)));

static __device__ __forceinline__ float rect_db_f(float xv) {
    return 6.020599913279624f * log2f(fabsf(xv) + 1e-8f);
}
static __device__ __forceinline__ float step_v(float s, float v) {
    return fmaxf(fmaf(A_AT, s, OMA_AT * v), fmaf(A_REL, s, OMA_REL * v));
}
static __device__ __forceinline__ float max3f(float a, float b, float c) {
    float d;
    asm("v_max3_f32 %0, %1, %2, %3" : "=v"(d) : "v"(a), "v"(b), "v"(c));
    return d;
}
static __device__ __forceinline__ float gain_mul(float s, float th, float dp) {
    float ddn = s - th;
    float gdn = 0.0f;
    if (ddn > -0.1f) {
        float dm = ddn - 0.1f;
        gdn = -0.4925037481259370f * (ddn + 0.1f + sqrtf(fmaf(dm, dm, 1e-4f)));
    }
    float dup = th - s;
    float gup = 0.0f;
    if (dup > -0.1f) {
        float um = dup - 0.1f;
        gup = 0.45f * (dup + 0.1f + sqrtf(fmaf(um, um, 1e-4f)));
    }
    gup = fminf(gup, 36.0f);
    return exp2f((gdn + gup) * dp * 0.1660964047443681f);
}

// ---- Pass 0: 9 composite coefficients per 8-sample oct (max-plus DP) ----
// K layout: [mg][plane 0..8][b*4 + slot]  (mg = group of 4 octs)
__global__ __launch_bounds__(256) void coef8_kernel(const float* __restrict__ x,
                                                    float* __restrict__ K) {
    int l = blockIdx.x * 256 + threadIdx.x;
    int slot = l & 3, b = (l >> 2) & 15, mg = l >> 6;
    int o = mg * 4 + slot;
    if (o >= N_OCT) return;
    const float4* xp = (const float4*)(x + (size_t)b * N_SAMP + (size_t)o * 8);
    float4 xa = xp[0], xb = xp[1];
    float vv[8];
    vv[0] = rect_db_f(xa.x); vv[1] = rect_db_f(xa.y);
    vv[2] = rect_db_f(xa.z); vv[3] = rect_db_f(xa.w);
    vv[4] = rect_db_f(xb.x); vv[5] = rect_db_f(xb.y);
    vv[6] = rect_db_f(xb.z); vv[7] = rect_db_f(xb.w);
    float c[9];
    c[0] = OMA_REL * vv[0];
    c[1] = OMA_AT * vv[0];
    #pragma unroll
    for (int j = 1; j < 8; ++j) {
        float p = OMA_AT * vv[j], q = OMA_REL * vv[j];
        c[j + 1] = fmaf(A_AT, c[j], p);
        #pragma unroll
        for (int m = j; m >= 1; --m)
            c[m] = fmaxf(fmaf(A_AT, c[m - 1], p), fmaf(A_REL, c[m], q));
        c[0] = fmaf(A_REL, c[0], q);
    }
    float* kp = K + (size_t)mg * MGF + (b * 4 + slot);
    #pragma unroll
    for (int pl = 0; pl < 9; ++pl) kp[pl * 64] = c[pl];
}

// ---- Pass 1: serial scan, 8-sample jumps.
//      7-slice LDS ring staged by global_load_lds (zero VGPR staging cost),
//      depth-7 pipeline with strict hand-counted vmcnt(45); 2-deep register
//      double-buffer (18 vf4) hides LDS read latency. Arch VGPR ~95: no
//      spill/motion hazard (rounds 2-3 post-mortem: asm tuples >240 VGPR
//      get spilled with loads in flight -> fault). ----
__global__ __launch_bounds__(64, 1) void scan8_kernel(const float* __restrict__ Kf,
                                                      const float* __restrict__ x,
                                                      float* __restrict__ lvl) {
    __shared__ vf4 smem[7 * 576];            // 64512 B (< 64 KB static limit)

    int wb = blockIdx.x;
    // m204 bijective XCD-chunked swizzle (54 = 8*6 + 6): consecutive chunks share L2
    int xcd = wb & 7, jj = wb >> 3;
    int w = (xcd < 6 ? xcd * 7 : 42 + (xcd - 6) * 6) + jj;
    const int lane = threadIdx.x;
    const int grp = lane >> 4, b = lane & 15;
    const int k = 4 * w + grp;               // chunk id 0..215 (256 octs each)

    constexpr double dAT = 0.9977349953069123, dRL = 0.9997732683378945;
    constexpr double dAT2 = dAT * dAT, dAT4 = dAT2 * dAT2;
    constexpr double dRL2 = dRL * dRL, dRL4 = dRL2 * dRL2;
    const float S0 = (float)(dRL4 * dRL4);
    const float S1 = (float)(dAT * dRL4 * dRL2 * dRL);
    const float S2 = (float)(dAT2 * dRL4 * dRL2);
    const float S3 = (float)(dAT2 * dAT * dRL4 * dRL);
    const float S4 = (float)(dAT4 * dRL4);
    const float S5 = (float)(dAT4 * dAT * dRL2 * dRL);
    const float S6 = (float)(dAT4 * dAT2 * dRL2);
    const float S7 = (float)(dAT4 * dAT2 * dAT * dRL);
    const float S8 = (float)(dAT4 * dAT4);

    vf4 rA[9], rB[9];                        // 72 VGPR reg double-buffer
    vf4 lv;
    float s;
    const char* gp;
    float* lq = lvl;
    float* dq = lvl + (size_t)16 * OPAD + lane * 4;  // dump slot (values unused)
    int sb = 0;
    unsigned kw = 0;

#define GLLDS(GPTR, LIDX)                                                        \
    __builtin_amdgcn_global_load_lds(                                            \
        (const __attribute__((address_space(1))) void*)(GPTR),                   \
        (__attribute__((address_space(3))) void*)&smem[(LIDX)], 16, 0, 0)

// Stage slice at slot SLOT from gp (per-lane global addr), advance gp.
#define STAGE(SLOT) do {                                                         \
    _Pragma("unroll")                                                            \
    for (int _j = 0; _j < 9; ++_j)                                               \
        GLLDS(gp + _j * 256, (SLOT) * 576 + _j * 64);                            \
    gp += MGB;                                                                   \
} while (0)

#define CMP(R) do {                                        \
    _Pragma("unroll")                                      \
    for (int _e = 0; _e < 4; ++_e) {                       \
        float c0 = fmaf(S0, s, R[0][_e]);                  \
        float c1 = fmaf(S1, s, R[1][_e]);                  \
        float c2 = fmaf(S2, s, R[2][_e]);                  \
        float c3 = fmaf(S3, s, R[3][_e]);                  \
        float c4 = fmaf(S4, s, R[4][_e]);                  \
        float c5 = fmaf(S5, s, R[5][_e]);                  \
        float c6 = fmaf(S6, s, R[6][_e]);                  \
        float c7 = fmaf(S7, s, R[7][_e]);                  \
        float c8 = fmaf(S8, s, R[8][_e]);                  \
        s = max3f(max3f(c0, c1, c2), max3f(c3, c4, c5), max3f(c6, c7, c8)); \
        lv[_e] = s;                                        \
    }                                                      \
} while (0)

// Phase p (slot = p%7, CUR = A iff p even):
//  1. vmcnt(45): slice p+1 resident (5 newer phases x 9 loads after its stage;
//     strict vs stores -> always correct, in-order vmcnt retirement).
//  2. ds_read next slice -> NXT (one full phase of LDS latency slack).
//  3. CMP on CUR (compiler auto-lgkm before uses).
//  4. store (flavor ST).
//  5. lgkmcnt(9): only NXT's reads outstanding -> CUR's slot reads drained,
//     safe to DMA-restage that slot.
//  6. restage slot with slice p+7.
#define PH(SLOT, CUR, NXT, ST) do {                                              \
    asm volatile("s_waitcnt vmcnt(45)" ::: "memory");                            \
    __builtin_amdgcn_sched_barrier(0);                                           \
    _Pragma("unroll")                                                            \
    for (int _j = 0; _j < 9; ++_j)                                               \
        NXT[_j] = smem[(((SLOT) + 1) % 7) * 576 + _j * 64 + lane];               \
    CMP(CUR);                                                                    \
    ST;                                                                          \
    asm volatile("s_waitcnt lgkmcnt(9)" ::: "memory");                           \
    STAGE(SLOT);                                                                 \
} while (0)

#define ST_W ((void)0)
#define ST_E do { *(vf4*)lq = lv; lq += 4; } while (0)
#define ST_D do {                                          \
    float* _sp = ((unsigned)(sb - kw) < 64u) ? lq : dq;    \
    *(vf4*)_sp = lv; lq += 4; ++sb;                        \
} while (0)

// 14-phase groups (period = lcm(7 slots, 2 reg buffers)), starting slot 0 / A:
#define G14(ST) do { \
    PH(0,rA,rB,ST); PH(1,rB,rA,ST); PH(2,rA,rB,ST); PH(3,rB,rA,ST); PH(4,rA,rB,ST); PH(5,rB,rA,ST); PH(6,rA,rB,ST); \
    PH(0,rB,rA,ST); PH(1,rA,rB,ST); PH(2,rB,rA,ST); PH(3,rA,rB,ST); PH(4,rB,rA,ST); PH(5,rA,rB,ST); PH(6,rB,rA,ST); \
} while (0)
#define PRE2(ST) do { PH(0,rA,rB,ST); PH(1,rB,rA,ST); } while (0)
// starting slot 2 / A (emit section follows warm's 1024 phases: 1024%7 == 2, even):
#define G14S2(ST) do { \
    PH(2,rA,rB,ST); PH(3,rB,rA,ST); PH(4,rA,rB,ST); PH(5,rB,rA,ST); PH(6,rA,rB,ST); PH(0,rB,rA,ST); PH(1,rA,rB,ST); \
    PH(2,rB,rA,ST); PH(3,rA,rB,ST); PH(4,rB,rA,ST); PH(5,rA,rB,ST); PH(6,rB,rA,ST); PH(0,rA,rB,ST); PH(1,rB,rA,ST); \
} while (0)
#define PRE8S2(ST) do { \
    PH(2,rA,rB,ST); PH(3,rB,rA,ST); PH(4,rA,rB,ST); PH(5,rB,rA,ST); PH(6,rA,rB,ST); PH(0,rB,rA,ST); PH(1,rA,rB,ST); PH(2,rB,rA,ST); \
} while (0)

// Prologue: stage slices 0..6 (63 loads = vmcnt capacity), wait slice 0
// (54 ops issued after it), read it into rA.
#define PROLOG() do {                                                            \
    _Pragma("unroll")                                                            \
    for (int _s = 0; _s < 7; ++_s) STAGE(_s);                                    \
    asm volatile("s_waitcnt vmcnt(54)" ::: "memory");                            \
    __builtin_amdgcn_sched_barrier(0);                                           \
    _Pragma("unroll")                                                            \
    for (int _j = 0; _j < 9; ++_j) rA[_j] = smem[_j * 64 + lane];                \
} while (0)

    if (w >= 4) {
        // full warmup: 4096 octs = 1024 macro-groups before the chunk
        const int g0 = (k - 16) * 64;                 // start macro-group
        s = rect_db_f(x[(size_t)b * N_SAMP + (size_t)g0 * 32]);
        asm volatile("" :: "v"(s));
        gp = (const char*)Kf + (size_t)g0 * MGB + (size_t)b * 16;
        PROLOG();
        // warm: 1024 phases = 73*14 + 2
        #pragma clang loop unroll(disable)
        for (int it = 0; it < 73; ++it) G14(ST_W);
        PRE2(ST_W);
        // emit: 64 phases = 4*14 + 8, continuing at slot 2 / parity A
        lq = lvl + (size_t)b * OPAD + (size_t)k * 256;    // [b][oct] layout
        #pragma clang loop unroll(disable)
        for (int it = 0; it < 4; ++it) G14S2(ST_E);
        PRE8S2(ST_E);
    } else {
        // chunks 0..15 start at sample 0 (exact history, no truncation).
        // Round phases up to a multiple of 14; overrun phases compute dead
        // state and store to the dump slot (reads stay within K: <=1043 MGs).
        s = rect_db_f(x[(size_t)b * N_SAMP]);
        asm volatile("" :: "v"(s));
        gp = (const char*)Kf + (size_t)b * 16;
        sb = 0;
        kw = (unsigned)(k << 6);                      // emit window [k*64, k*64+64)
        lq = lvl + (size_t)b * OPAD;
        PROLOG();
        const int qs = (256 * (w + 1) + 13) / 14;     // 19,37,55,74
        #pragma clang loop unroll(disable)
        for (int it = 0; it < qs; ++it) G14(ST_D);
    }
    asm volatile("s_waitcnt vmcnt(0)" ::: "memory");

#undef GLLDS
#undef STAGE
#undef CMP
#undef PH
#undef ST_W
#undef ST_E
#undef ST_D
#undef G14
#undef PRE2
#undef G14S2
#undef PRE8S2
#undef PROLOG
}

// ---- Pass 2: intra-oct reconstruction + gain + output (parallel) ----
__global__ __launch_bounds__(256) void out8_kernel(const float* __restrict__ x,
                                                   const float* __restrict__ lvl,
                                                   const float* __restrict__ thr,
                                                   const float* __restrict__ dep,
                                                   float* __restrict__ out) {
    int o = blockIdx.x * 256 + threadIdx.x;
    int b = blockIdx.y;
    if (o >= N_OCT) return;
    const float4* xp = (const float4*)(x + (size_t)b * N_SAMP + (size_t)o * 8);
    float4 xa = xp[0], xb = xp[1];
    float v0 = rect_db_f(xa.x), v1 = rect_db_f(xa.y);
    float v2 = rect_db_f(xa.z), v3 = rect_db_f(xa.w);
    float v4 = rect_db_f(xb.x), v5 = rect_db_f(xb.y);
    float v6 = rect_db_f(xb.z), v7 = rect_db_f(xb.w);
    float s = (o == 0) ? v0 : lvl[(size_t)b * OPAD + o - 1];   // coalesced
    float l0 = step_v(s, v0);
    float l1 = step_v(l0, v1);
    float l2 = step_v(l1, v2);
    float l3 = step_v(l2, v3);
    float l4 = step_v(l3, v4);
    float l5 = step_v(l4, v5);
    float l6 = step_v(l5, v6);
    float l7 = step_v(l6, v7);
    float th = fmaf(thr[b], 40.0f, -40.0f);
    float dp = dep[b];
    float4 oa, ob;
    oa.x = xa.x * gain_mul(l0, th, dp);
    oa.y = xa.y * gain_mul(l1, th, dp);
    oa.z = xa.z * gain_mul(l2, th, dp);
    oa.w = xa.w * gain_mul(l3, th, dp);
    ob.x = xb.x * gain_mul(l4, th, dp);
    ob.y = xb.y * gain_mul(l5, th, dp);
    ob.z = xb.z * gain_mul(l6, th, dp);
    ob.w = xb.w * gain_mul(l7, th, dp);
    float4* op = (float4*)(out + (size_t)b * N_SAMP + (size_t)o * 8);
    op[0] = oa;
    op[1] = ob;
}

// ---- Fallback (tiny ws): slow but correct fused scan ----
__global__ __launch_bounds__(64) void scan_fused(const float* __restrict__ x,
                                                 const float* __restrict__ thr,
                                                 const float* __restrict__ dep,
                                                 float* __restrict__ out) {
    int t = blockIdx.x * 64 + threadIdx.x;
    const int NCH = 54, CH = 8192, WM = 32768;
    if (t >= BATCH * NCH) return;
    int b = t / NCH, k = t - b * NCH;
    int start = k * CH, end = min(start + CH, N_SAMP), w0 = max(start - WM, 0);
    const float* xr = x + (size_t)b * N_SAMP;
    float th = fmaf(thr[b], 40.0f, -40.0f);
    float dp = dep[b];
    float s = rect_db_f(xr[w0]);
    for (int j = w0; j < start; ++j) s = step_v(s, rect_db_f(xr[j]));
    float* orow = out + (size_t)b * N_SAMP;
    for (int j = start; j < end; ++j) {
        float xv = xr[j];
        s = step_v(s, rect_db_f(xv));
        orow[j] = xv * gain_mul(s, th, dp);
    }
}

extern "C" void kernel_launch(void* const* d_in, const int* in_sizes, int n_in,
                              void* d_out, int out_size, void* d_ws, size_t ws_size,
                              hipStream_t stream) {
    const float* x   = (const float*)d_in[0];
    const float* thr = (const float*)d_in[1];
    const float* dep = (const float*)d_in[2];
    float* out = (float*)d_out;

    const size_t k_bytes   = (size_t)NMG * MGF * sizeof(float);            // 31.85 MB
    const size_t lvl_bytes = ((size_t)16 * OPAD + 512) * sizeof(float);    // 3.54 MB + dump

    if (ws_size >= k_bytes + lvl_bytes) {
        float* K   = (float*)d_ws;
        float* lvl = (float*)((char*)d_ws + k_bytes);
        coef8_kernel<<<(NMG * 64) / 256, 256, 0, stream>>>(x, K);
        scan8_kernel<<<NWAVE, 64, 0, stream>>>(K, x, lvl);
        dim3 gpar((N_OCT + 255) / 256, BATCH);
        out8_kernel<<<gpar, 256, 0, stream>>>(x, lvl, thr, dep, out);
    } else {
        scan_fused<<<(BATCH * 54 + 63) / 64, 64, 0, stream>>>(x, thr, dep, out);
    }
}

// Round 8
// 285.847 us; speedup vs baseline: 1.1526x; 1.1526x over previous
//
#include <hip/hip_runtime.h>
#include <math.h>

// ---- problem constants ----
#define N_SAMP 441000
#define BATCH  16
#define G_LAST 27562           // last (partial: 8-sample) 16-group; N16 = 27563
#define LPAD   27648           // padded groups16: 108 chunks * 256
#define NMG16  6912            // LPAD/4 macro-groups (4 groups each, 64 samples)
#define MGF16  1088            // floats per macro-group: 17 planes * 64 (16b*4slot)
#define MGB16  4352            // bytes per macro-group
#define NWAVE  27              // 108 chunks / 4 per wave

#define A_AT  0.9977349953069123f
#define A_REL 0.9997732683378945f
#define OMA_AT  (1.0f - A_AT)
#define OMA_REL (1.0f - A_REL)

typedef float vf4 __attribute__((ext_vector_type(4)));

static __device__ __forceinline__ float rect_db_f(float xv) {
    return 6.020599913279624f * log2f(fabsf(xv) + 1e-8f);
}
static __device__ __forceinline__ float step_v(float s, float v) {
    return fmaxf(fmaf(A_AT, s, OMA_AT * v), fmaf(A_REL, s, OMA_REL * v));
}
static __device__ __forceinline__ float max3f(float a, float b, float c) {
    float d;
    asm("v_max3_f32 %0, %1, %2, %3" : "=v"(d) : "v"(a), "v"(b), "v"(c));
    return d;
}
static __device__ __forceinline__ float gain_mul(float s, float th, float dp) {
    float ddn = s - th;
    float gdn = 0.0f;
    if (ddn > -0.1f) {
        float dm = ddn - 0.1f;
        gdn = -0.4925037481259370f * (ddn + 0.1f + sqrtf(fmaf(dm, dm, 1e-4f)));
    }
    float dup = th - s;
    float gup = 0.0f;
    if (dup > -0.1f) {
        float um = dup - 0.1f;
        gup = 0.45f * (dup + 0.1f + sqrtf(fmaf(um, um, 1e-4f)));
    }
    gup = fminf(gup, 36.0f);
    return exp2f((gdn + gup) * dp * 0.1660964047443681f);
}

// slopes A_AT^m * A_REL^(16-m)
constexpr double dpw(double xx, int n) {
    double r = 1.0;
    for (int i = 0; i < n; ++i) r *= xx;
    return r;
}
#define DAT 0.9977349953069123
#define DRL 0.9997732683378945
constexpr float SC0  = (float)(dpw(DRL, 16));
constexpr float SC1  = (float)(dpw(DAT, 1)  * dpw(DRL, 15));
constexpr float SC2  = (float)(dpw(DAT, 2)  * dpw(DRL, 14));
constexpr float SC3  = (float)(dpw(DAT, 3)  * dpw(DRL, 13));
constexpr float SC4  = (float)(dpw(DAT, 4)  * dpw(DRL, 12));
constexpr float SC5  = (float)(dpw(DAT, 5)  * dpw(DRL, 11));
constexpr float SC6  = (float)(dpw(DAT, 6)  * dpw(DRL, 10));
constexpr float SC7  = (float)(dpw(DAT, 7)  * dpw(DRL, 9));
constexpr float SC8  = (float)(dpw(DAT, 8)  * dpw(DRL, 8));
constexpr float SC9  = (float)(dpw(DAT, 9)  * dpw(DRL, 7));
constexpr float SC10 = (float)(dpw(DAT, 10) * dpw(DRL, 6));
constexpr float SC11 = (float)(dpw(DAT, 11) * dpw(DRL, 5));
constexpr float SC12 = (float)(dpw(DAT, 12) * dpw(DRL, 4));
constexpr float SC13 = (float)(dpw(DAT, 13) * dpw(DRL, 3));
constexpr float SC14 = (float)(dpw(DAT, 14) * dpw(DRL, 2));
constexpr float SC15 = (float)(dpw(DAT, 15) * dpw(DRL, 1));
constexpr float SC16 = (float)(dpw(DAT, 16));

// ---- Pass 0: 17 composite coefficients per 16-sample group (max-plus DP) ----
// K layout: [mg][plane 0..16][b*4 + slot]  (mg = group of 4 groups16)
__global__ __launch_bounds__(256) void coef16_kernel(const float* __restrict__ x,
                                                     float* __restrict__ K) {
    int l = blockIdx.x * 256 + threadIdx.x;
    int slot = l & 3, b = (l >> 2) & 15, mg = l >> 6;
    int g = mg * 4 + slot;
    if (g > G_LAST) return;
    const float4* xp = (const float4*)(x + (size_t)b * N_SAMP + (size_t)g * 16);
    float vv[16];
    float4 xa = xp[0], xb = xp[1];
    vv[0] = rect_db_f(xa.x); vv[1] = rect_db_f(xa.y);
    vv[2] = rect_db_f(xa.z); vv[3] = rect_db_f(xa.w);
    vv[4] = rect_db_f(xb.x); vv[5] = rect_db_f(xb.y);
    vv[6] = rect_db_f(xb.z); vv[7] = rect_db_f(xb.w);
    if (g < G_LAST) {
        float4 xc = xp[2], xd = xp[3];
        vv[8]  = rect_db_f(xc.x); vv[9]  = rect_db_f(xc.y);
        vv[10] = rect_db_f(xc.z); vv[11] = rect_db_f(xc.w);
        vv[12] = rect_db_f(xd.x); vv[13] = rect_db_f(xd.y);
        vv[14] = rect_db_f(xd.z); vv[15] = rect_db_f(xd.w);
    } else {
        // boundary group: only 8 valid samples; pad (states after are unused)
        #pragma unroll
        for (int i = 8; i < 16; ++i) vv[i] = vv[7];
    }
    float c[17];
    c[0] = OMA_REL * vv[0];
    c[1] = OMA_AT * vv[0];
    #pragma unroll
    for (int j = 1; j < 16; ++j) {
        float p = OMA_AT * vv[j], q = OMA_REL * vv[j];
        c[j + 1] = fmaf(A_AT, c[j], p);
        #pragma unroll
        for (int m = j; m >= 1; --m)
            c[m] = fmaxf(fmaf(A_AT, c[m - 1], p), fmaf(A_REL, c[m], q));
        c[0] = fmaf(A_REL, c[0], q);
    }
    float* kp = K + (size_t)mg * MGF16 + (b * 4 + slot);
    #pragma unroll
    for (int pl = 0; pl < 17; ++pl) kp[pl * 64] = c[pl];
}

// ---- Pass 1: serial scan, 16-sample jumps, strictly inside the PROVEN R1
//      asm envelope: depth-2 rotation (34 quads = 136 VGPR < proven-safe 36),
//      POSITIVE-ONLY saddr immediates (two base regs va, vb=va+2304), no
//      touch loads, uniform hand-counted vmcnt(17). ----
__global__ __launch_bounds__(64, 1) void scan16_kernel(const float* __restrict__ Kf,
                                                       const float* __restrict__ x,
                                                       float* __restrict__ lvl) {
    int wb = blockIdx.x;
    // bijective XCD-chunked swizzle for 27 = 8*3+3 (m204 form)
    int xcd = wb & 7, jj = wb >> 3;
    int w = (xcd < 3 ? xcd * 4 : 12 + (xcd - 3) * 3) + jj;
    const int lane = threadIdx.x;
    const int grp = lane >> 4, b = lane & 15;
    const int k = 4 * w + grp;               // chunk id 0..107 (256 groups16 each)

    vf4 R0[17], R1[17];                      // 136 VGPRs, reg-resident
    vf4 lv;
    float s;
    unsigned va, vb;                         // plane0 base, plane9 base (va+2304)
    float* lq;
    float* dq = lvl + (size_t)16 * LPAD + lane * 4;   // dump slot (values unused)

#define SB() __builtin_amdgcn_sched_barrier(0)

// 17 planes, positive imms only: planes 0..8 from va (0..2048),
// planes 9..16 from vb = va + 2304 (0..1792). Both advance MGB16/phase.
#define LDB(R) do {                                                                              \
    asm volatile("global_load_dwordx4 %0, %1, %2 offset:0"    : "=v"(R[0])  : "v"(va), "s"(Kf)); \
    asm volatile("global_load_dwordx4 %0, %1, %2 offset:256"  : "=v"(R[1])  : "v"(va), "s"(Kf)); \
    asm volatile("global_load_dwordx4 %0, %1, %2 offset:512"  : "=v"(R[2])  : "v"(va), "s"(Kf)); \
    asm volatile("global_load_dwordx4 %0, %1, %2 offset:768"  : "=v"(R[3])  : "v"(va), "s"(Kf)); \
    asm volatile("global_load_dwordx4 %0, %1, %2 offset:1024" : "=v"(R[4])  : "v"(va), "s"(Kf)); \
    asm volatile("global_load_dwordx4 %0, %1, %2 offset:1280" : "=v"(R[5])  : "v"(va), "s"(Kf)); \
    asm volatile("global_load_dwordx4 %0, %1, %2 offset:1536" : "=v"(R[6])  : "v"(va), "s"(Kf)); \
    asm volatile("global_load_dwordx4 %0, %1, %2 offset:1792" : "=v"(R[7])  : "v"(va), "s"(Kf)); \
    asm volatile("global_load_dwordx4 %0, %1, %2 offset:2048" : "=v"(R[8])  : "v"(va), "s"(Kf)); \
    asm volatile("global_load_dwordx4 %0, %1, %2 offset:0"    : "=v"(R[9])  : "v"(vb), "s"(Kf)); \
    asm volatile("global_load_dwordx4 %0, %1, %2 offset:256"  : "=v"(R[10]) : "v"(vb), "s"(Kf)); \
    asm volatile("global_load_dwordx4 %0, %1, %2 offset:512"  : "=v"(R[11]) : "v"(vb), "s"(Kf)); \
    asm volatile("global_load_dwordx4 %0, %1, %2 offset:768"  : "=v"(R[12]) : "v"(vb), "s"(Kf)); \
    asm volatile("global_load_dwordx4 %0, %1, %2 offset:1024" : "=v"(R[13]) : "v"(vb), "s"(Kf)); \
    asm volatile("global_load_dwordx4 %0, %1, %2 offset:1280" : "=v"(R[14]) : "v"(vb), "s"(Kf)); \
    asm volatile("global_load_dwordx4 %0, %1, %2 offset:1536" : "=v"(R[15]) : "v"(vb), "s"(Kf)); \
    asm volatile("global_load_dwordx4 %0, %1, %2 offset:1792" : "=v"(R[16]) : "v"(vb), "s"(Kf)); \
    va += MGB16;                                                                                 \
    vb += MGB16;                                                                                 \
} while (0)

// depth-2: at the wait for buffer R (slice p), ops issued after its 17 loads
// = [<=1 store] + 17 loads of slice p+1. vmcnt(17) => all but the newest 17
// retired => slice p resident (in-order retirement; a store in the stream
// only over-tightens by one).
#define WAIT17() do {                                      \
    asm volatile("s_waitcnt vmcnt(17)" ::: "memory");      \
    SB();                                                  \
} while (0)

#define CMP(R) do {                                        \
    _Pragma("unroll")                                      \
    for (int _e = 0; _e < 4; ++_e) {                       \
        float c0  = fmaf(SC0,  s, R[0][_e]);               \
        float c1  = fmaf(SC1,  s, R[1][_e]);               \
        float c2  = fmaf(SC2,  s, R[2][_e]);               \
        float c3  = fmaf(SC3,  s, R[3][_e]);               \
        float c4  = fmaf(SC4,  s, R[4][_e]);               \
        float c5  = fmaf(SC5,  s, R[5][_e]);               \
        float c6  = fmaf(SC6,  s, R[6][_e]);               \
        float c7  = fmaf(SC7,  s, R[7][_e]);               \
        float c8  = fmaf(SC8,  s, R[8][_e]);               \
        float c9  = fmaf(SC9,  s, R[9][_e]);               \
        float c10 = fmaf(SC10, s, R[10][_e]);              \
        float c11 = fmaf(SC11, s, R[11][_e]);              \
        float c12 = fmaf(SC12, s, R[12][_e]);              \
        float c13 = fmaf(SC13, s, R[13][_e]);              \
        float c14 = fmaf(SC14, s, R[14][_e]);              \
        float c15 = fmaf(SC15, s, R[15][_e]);              \
        float c16 = fmaf(SC16, s, R[16][_e]);              \
        float t0 = max3f(c0, c1, c2);                      \
        float t1 = max3f(c3, c4, c5);                      \
        float t2 = max3f(c6, c7, c8);                      \
        float t3 = max3f(c9, c10, c11);                    \
        float t4 = max3f(c12, c13, c14);                   \
        s = max3f(max3f(t0, t1, t2), max3f(t3, t4, c15), c16); \
        lv[_e] = s;                                        \
    }                                                      \
} while (0)

#define ST_W ((void)0)
#define ST_E do { *(vf4*)lq = lv; lq += 4; } while (0)
#define ST_D do {                                          \
    float* _sp = ((unsigned)(sb - kw) < 64u) ? lq : dq;    \
    *(vf4*)_sp = lv; lq += 4; ++sb;                        \
} while (0)

#define PH_A(ST) do { WAIT17(); CMP(R0); ST; SB(); LDB(R0); SB(); } while (0)
#define PH_B(ST) do { WAIT17(); CMP(R1); ST; SB(); LDB(R1); SB(); } while (0)

// Prologue: slices 0 and 1 in flight -> phase 0's WAIT17 retires slice 0.
#define PROLOG() do { LDB(R0); LDB(R1); SB(); } while (0)

    if (w >= 2) {
        // full warmup: 8 chunks = 512 MGs = 32768 samples before the chunk
        const int mg0 = (k - 8) * 64;                 // start MG
        s = rect_db_f(x[(size_t)b * N_SAMP + (size_t)mg0 * 64]);
        asm volatile("" :: "v"(s));                   // pin: x-load retired pre-asm
        va = (unsigned)mg0 * MGB16 + (unsigned)b * 16u;
        vb = va + 2304u;
        PROLOG();
        // warm: 512 phases = 256 pairs
        #pragma clang loop unroll(disable)
        for (int it = 0; it < 256; ++it) { PH_A(ST_W); PH_B(ST_W); }
        // emit: 64 phases = 32 pairs
        lq = lvl + (size_t)b * LPAD + (size_t)k * 256;    // [b][group16] layout
        #pragma clang loop unroll(disable)
        for (int it = 0; it < 32; ++it) { PH_A(ST_E); PH_B(ST_E); }
    } else {
        // chunks 0..7 start at sample 0 (exact history, no truncation);
        // wave-uniform phase count, out-of-window phases store to dump slot.
        s = rect_db_f(x[(size_t)b * N_SAMP]);
        asm volatile("" :: "v"(s));
        va = (unsigned)b * 16u;
        vb = va + 2304u;
        int sb = 0;
        const unsigned kw = (unsigned)(k * 64);       // emit window [k*64, k*64+64)
        lq = lvl + (size_t)b * LPAD;
        PROLOG();
        const int np = (4 * w + 4) * 32;              // pairs: 128 (w=0) / 256 (w=1)
        #pragma clang loop unroll(disable)
        for (int it = 0; it < np; ++it) { PH_A(ST_D); PH_B(ST_D); }
    }
    asm volatile("s_waitcnt vmcnt(0)" ::: "memory");

#undef SB
#undef LDB
#undef WAIT17
#undef CMP
#undef ST_W
#undef ST_E
#undef ST_D
#undef PH_A
#undef PH_B
#undef PROLOG
}

// ---- Pass 2: intra-group reconstruction + gain + output (parallel) ----
__global__ __launch_bounds__(256) void out16_kernel(const float* __restrict__ x,
                                                    const float* __restrict__ lvl,
                                                    const float* __restrict__ thr,
                                                    const float* __restrict__ dep,
                                                    float* __restrict__ out) {
    int g = blockIdx.x * 256 + threadIdx.x;
    int b = blockIdx.y;
    if (g > G_LAST) return;
    const float4* xp = (const float4*)(x + (size_t)b * N_SAMP + (size_t)g * 16);
    float4 xa = xp[0], xb = xp[1];
    float v0 = rect_db_f(xa.x), v1 = rect_db_f(xa.y);
    float v2 = rect_db_f(xa.z), v3 = rect_db_f(xa.w);
    float v4 = rect_db_f(xb.x), v5 = rect_db_f(xb.y);
    float v6 = rect_db_f(xb.z), v7 = rect_db_f(xb.w);
    float s = (g == 0) ? v0 : lvl[(size_t)b * LPAD + g - 1];   // coalesced
    float th = fmaf(thr[b], 40.0f, -40.0f);
    float dp = dep[b];
    float l0 = step_v(s, v0);
    float l1 = step_v(l0, v1);
    float l2 = step_v(l1, v2);
    float l3 = step_v(l2, v3);
    float l4 = step_v(l3, v4);
    float l5 = step_v(l4, v5);
    float l6 = step_v(l5, v6);
    float l7 = step_v(l6, v7);
    float4 oa, ob;
    oa.x = xa.x * gain_mul(l0, th, dp);
    oa.y = xa.y * gain_mul(l1, th, dp);
    oa.z = xa.z * gain_mul(l2, th, dp);
    oa.w = xa.w * gain_mul(l3, th, dp);
    ob.x = xb.x * gain_mul(l4, th, dp);
    ob.y = xb.y * gain_mul(l5, th, dp);
    ob.z = xb.z * gain_mul(l6, th, dp);
    ob.w = xb.w * gain_mul(l7, th, dp);
    float4* op = (float4*)(out + (size_t)b * N_SAMP + (size_t)g * 16);
    op[0] = oa;
    op[1] = ob;
    if (g < G_LAST) {
        float4 xc = xp[2], xd = xp[3];
        float v8  = rect_db_f(xc.x), v9  = rect_db_f(xc.y);
        float v10 = rect_db_f(xc.z), v11 = rect_db_f(xc.w);
        float v12 = rect_db_f(xd.x), v13 = rect_db_f(xd.y);
        float v14 = rect_db_f(xd.z), v15 = rect_db_f(xd.w);
        float l8  = step_v(l7, v8);
        float l9  = step_v(l8, v9);
        float l10 = step_v(l9, v10);
        float l11 = step_v(l10, v11);
        float l12 = step_v(l11, v12);
        float l13 = step_v(l12, v13);
        float l14 = step_v(l13, v14);
        float l15 = step_v(l14, v15);
        float4 oc, od;
        oc.x = xc.x * gain_mul(l8,  th, dp);
        oc.y = xc.y * gain_mul(l9,  th, dp);
        oc.z = xc.z * gain_mul(l10, th, dp);
        oc.w = xc.w * gain_mul(l11, th, dp);
        od.x = xd.x * gain_mul(l12, th, dp);
        od.y = xd.y * gain_mul(l13, th, dp);
        od.z = xd.z * gain_mul(l14, th, dp);
        od.w = xd.w * gain_mul(l15, th, dp);
        op[2] = oc;
        op[3] = od;
    }
}

// ---- Fallback (tiny ws): slow but correct fused scan ----
__global__ __launch_bounds__(64) void scan_fused(const float* __restrict__ x,
                                                 const float* __restrict__ thr,
                                                 const float* __restrict__ dep,
                                                 float* __restrict__ out) {
    int t = blockIdx.x * 64 + threadIdx.x;
    const int NCH = 54, CH = 8192, WM = 32768;
    if (t >= BATCH * NCH) return;
    int b = t / NCH, k = t - b * NCH;
    int start = k * CH, end = min(start + CH, N_SAMP), w0 = max(start - WM, 0);
    const float* xr = x + (size_t)b * N_SAMP;
    float th = fmaf(thr[b], 40.0f, -40.0f);
    float dp = dep[b];
    float s = rect_db_f(xr[w0]);
    for (int j = w0; j < start; ++j) s = step_v(s, rect_db_f(xr[j]));
    float* orow = out + (size_t)b * N_SAMP;
    for (int j = start; j < end; ++j) {
        float xv = xr[j];
        s = step_v(s, rect_db_f(xv));
        orow[j] = xv * gain_mul(s, th, dp);
    }
}

extern "C" void kernel_launch(void* const* d_in, const int* in_sizes, int n_in,
                              void* d_out, int out_size, void* d_ws, size_t ws_size,
                              hipStream_t stream) {
    const float* x   = (const float*)d_in[0];
    const float* thr = (const float*)d_in[1];
    const float* dep = (const float*)d_in[2];
    float* out = (float*)d_out;

    const size_t k_bytes   = (size_t)NMG16 * MGF16 * sizeof(float);        // 30.08 MB
    const size_t lvl_bytes = ((size_t)16 * LPAD + 512) * sizeof(float);    // 1.77 MB + dump

    if (ws_size >= k_bytes + lvl_bytes) {
        float* K   = (float*)d_ws;
        float* lvl = (float*)((char*)d_ws + k_bytes);
        coef16_kernel<<<(NMG16 * 64) / 256, 256, 0, stream>>>(x, K);
        scan16_kernel<<<NWAVE, 64, 0, stream>>>(K, x, lvl);
        dim3 gpar((G_LAST + 1 + 255) / 256, BATCH);
        out16_kernel<<<gpar, 256, 0, stream>>>(x, lvl, thr, dep, out);
    } else {
        scan_fused<<<(BATCH * 54 + 63) / 64, 64, 0, stream>>>(x, thr, dep, out);
    }
}